// Round 9
// baseline (3309.912 us; speedup 1.0000x reference)
//
#include <hip/hip_runtime.h>
#include <hip/hip_bf16.h>
#include <stdint.h>

typedef __attribute__((ext_vector_type(8))) __bf16 bf16x8;
typedef __attribute__((ext_vector_type(4))) float  floatx4;

#define T_STEPS 256
#define BATCH   128
#define HID     512
#define POLL_CAP 2000000

__device__ __forceinline__ float sigmoidf_(float x) { return 1.f / (1.f + __expf(-x)); }
__device__ __forceinline__ float tanhf_(float y) {
  float e = __expf(-2.f * fabsf(y));
  return copysignf((1.f - e) / (1.f + e), y);
}

// L1-bypassing (sc0) flag load: reads the XCD-shared L2 directly.
__device__ __forceinline__ int load_sc0(const int* p) {
  int v;
  asm volatile("global_load_dword %0, %1, off sc0\n\t"
               "s_waitcnt vmcnt(0)"
               : "=v"(v) : "v"(p) : "memory");
  return v;
}

// XCD-local persistent GRU.
// 8 rings = [layer(2)] x [bq(4): 32 batch rows], each ring = 32 blocks pinned to
// ONE XCD (runtime claim via HW_REG_XCC_ID + atomicAdd). Block = slot: owns 16
// hidden cols [16*slot, +16) for its ring's 32 rows.
// Waves: w0/w1/w2 = gate waves (r/z/n), W entirely in registers (Wreg[0..15] =
// h-part, Wreg[16..31] = x-part); w3 = publisher (layer 0 only).
// Intra-ring h exchange: plain stores -> shared XCD L2; window-8 local slabs;
// consumers do buffer_inv (L1-only, cheap) then plain b128 loads; flags =
// plain-stored private lines polled with sc0 loads. All intra traffic stays in
// the XCD's L2 -> chain RTs ~150cy instead of ~2us fabric RTs.
// Cross-layer: w3 republishes h0 slab to a global array with sc1 atomic stores,
// pipelined drain (vmcnt(9)) and a 2-step-lagged cross flag; layer-1 reads it
// with plain cached loads (fresh addresses).
__global__ __launch_bounds__(256, 1) void gru_xcd(
    const float* __restrict__ x,                         // [128][256][256] fp32
    const float* __restrict__ Wih0, const float* __restrict__ Whh0,
    const float* __restrict__ bih0, const float* __restrict__ bhh0,
    const float* __restrict__ Wih1, const float* __restrict__ Whh1,
    const float* __restrict__ bih1, const float* __restrict__ bhh1,
    __bf16* __restrict__ h0g,                            // [256][128][512]
    __bf16* __restrict__ larena,                         // [8][8][32][512]
    int* __restrict__ claim,                             // [8]
    int* __restrict__ iflags,                            // [8][32][32]
    int* __restrict__ cflags)                            // [4][32][32]
{
  __shared__ int s_ring, s_slot;
  __shared__ float LZ[2][16][16], LNA[2][16][16], LNB[2][16][16];
  __shared__ uint32_t LH[2][256];

  const int tid = threadIdx.x;
  if (tid == 0) {
    int xcc;
    asm volatile("s_getreg_b32 %0, hwreg(HW_REG_XCC_ID)" : "=s"(xcc));
    xcc &= 7;
    s_ring = xcc;
    s_slot = atomicAdd(&claim[xcc], 1);
  }
  __syncthreads();
  const int  ring  = s_ring;
  const bool valid = (s_slot < 32);
  const int  slot  = s_slot & 31;
  const int  layer = ring >> 2;
  const int  bq    = ring & 3;
  const int  w = tid >> 6, l = tid & 63, c = l & 15, q = l >> 4;
  const int  jj0 = slot * 16;
  const int  Kin = layer ? HID : 256;
  const int  KTx = Kin >> 5;                 // 8 (layer0) or 16 (layer1)

  const float* Wih = layer ? Wih1 : Wih0;
  const float* Whh = layer ? Whh1 : Whh0;
  const float* bih = layer ? bih1 : bih0;
  const float* bhh = layer ? bhh1 : bhh0;

  __bf16* lbase = larena + (size_t)ring * 8 * 32 * HID;   // ring's 8-slab window
  int* ifl = iflags + ring * 32 * 32;
  int* cfl = cflags + bq * 32 * 32;

  // ---- W into registers (gate waves). Wreg[0..15]=h-part, Wreg[16..31]=x-part.
  bf16x8 Wreg[32];
  if (w < 3) {
    const int grow = w * HID + jj0 + c;      // gate w: 0=r,1=z,2=n
    const float* wih_r = Wih + (size_t)grow * Kin;
    const float* whh_r = Whh + (size_t)grow * HID;
    #pragma unroll
    for (int kt = 0; kt < 16; ++kt) {
      const float* s = whh_r + kt * 32 + q * 8;
      bf16x8 v;
      #pragma unroll
      for (int j = 0; j < 8; ++j) v[j] = (__bf16)s[j];
      Wreg[kt] = v;
    }
    #pragma unroll
    for (int kt = 0; kt < 16; ++kt) {
      if (kt < KTx) {
        const float* s = wih_r + kt * 32 + q * 8;
        bf16x8 v;
        #pragma unroll
        for (int j = 0; j < 8; ++j) v[j] = (__bf16)s[j];
        Wreg[16 + kt] = v;
      }
    }
  }

  // ---- biases (used by w0's epilogue; col jj0+c)
  float b_r, b_z, b_nx, b_nh;
  {
    int jj = jj0 + c;
    b_r  = bih[jj] + bhh[jj];
    b_z  = bih[HID + jj] + bhh[HID + jj];
    b_nx = bih[2 * HID + jj];
    b_nh = bhh[2 * HID + jj];
  }

  floatx4 accA[2], accB[2];
  const floatx4 z4 = {0.f, 0.f, 0.f, 0.f};
  float hprev[2][4] = {{0.f,0.f,0.f,0.f},{0.f,0.f,0.f,0.f}};
  bool alive = valid;

  auto phaseX = [&](int t) {
    accA[0] = z4; accA[1] = z4;
    if (layer == 0) {
      #pragma unroll
      for (int mt = 0; mt < 2; ++mt) {
        int row = bq * 32 + mt * 16 + c;
        const float* xp = x + ((size_t)row * T_STEPS + t) * 256 + q * 8;
        #pragma unroll
        for (int kt = 0; kt < 8; ++kt) {
          floatx4 u = *(const floatx4*)(xp + kt * 32);
          floatx4 v = *(const floatx4*)(xp + kt * 32 + 4);
          bf16x8 a;
          a[0]=(__bf16)u[0]; a[1]=(__bf16)u[1]; a[2]=(__bf16)u[2]; a[3]=(__bf16)u[3];
          a[4]=(__bf16)v[0]; a[5]=(__bf16)v[1]; a[6]=(__bf16)v[2]; a[7]=(__bf16)v[3];
          accA[mt] = __builtin_amdgcn_mfma_f32_16x16x32_bf16(a, Wreg[16 + kt], accA[mt], 0, 0, 0);
        }
      }
    } else {
      #pragma unroll
      for (int mt = 0; mt < 2; ++mt) {
        int row = bq * 32 + mt * 16 + c;
        const __bf16* xp = h0g + ((size_t)t * BATCH + row) * HID + q * 8;
        #pragma unroll
        for (int kt = 0; kt < 16; ++kt) {
          bf16x8 a = *(const bf16x8*)(xp + kt * 32);
          accA[mt] = __builtin_amdgcn_mfma_f32_16x16x32_bf16(a, Wreg[16 + kt], accA[mt], 0, 0, 0);
        }
      }
    }
  };

  auto phaseH = [&](int tprev) {     // reads local slab tprev
    accB[0] = z4; accB[1] = z4;
    const __bf16* hb = lbase + (size_t)(tprev & 7) * 32 * HID;
    #pragma unroll
    for (int mt = 0; mt < 2; ++mt) {
      const __bf16* hp = hb + (size_t)(mt * 16 + c) * HID + q * 8;
      #pragma unroll
      for (int kt = 0; kt < 16; ++kt) {
        bf16x8 a = *(const bf16x8*)(hp + kt * 32);
        accB[mt] = __builtin_amdgcn_mfma_f32_16x16x32_bf16(a, Wreg[kt], accB[mt], 0, 0, 0);
      }
    }
  };

  auto polli = [&](int target) {     // intra-ring: sc0 loads of local L2 flags
    if (!alive) return;
    const int* p = ifl + (l & 31) * 32;
    int it = 0;
    while (1) {
      int v = load_sc0(p);
      if (__all(v >= target)) break;
      if (++it > POLL_CAP) { alive = false; break; }
      __builtin_amdgcn_s_sleep(1);
    }
  };
  auto pollc = [&](int target) {     // cross-layer: bypassing agent loads (L3)
    if (!alive) return;
    const int* p = cfl + (l & 31) * 32;
    int it = 0;
    while (1) {
      int v = __hip_atomic_load(p, __ATOMIC_RELAXED, __HIP_MEMORY_SCOPE_AGENT);
      if (__all(v >= target)) break;
      if (++it > POLL_CAP) { alive = false; break; }
      __builtin_amdgcn_s_sleep(1);
    }
  };

  // ---- prologue
  if (w < 3) {
    if (layer == 1) pollc(1);
    phaseX(0);
  }

  for (int t = 0; t < T_STEPS; ++t) {
    if (w < 3) {
      if (t > 0) {
        polli(t);                                   // peers posted slab t-1
        asm volatile("buffer_inv" ::: "memory");    // L1-only inv (window reuse)
        phaseH(t - 1);
      } else {
        accB[0] = z4; accB[1] = z4;
      }
      if (w == 1) {
        #pragma unroll
        for (int mt = 0; mt < 2; ++mt)
          #pragma unroll
          for (int rg = 0; rg < 4; ++rg)
            LZ[mt][q * 4 + rg][c] = accA[mt][rg] + accB[mt][rg];
      } else if (w == 2) {
        #pragma unroll
        for (int mt = 0; mt < 2; ++mt)
          #pragma unroll
          for (int rg = 0; rg < 4; ++rg) {
            LNA[mt][q * 4 + rg][c] = accA[mt][rg];
            LNB[mt][q * 4 + rg][c] = accB[mt][rg];
          }
      }
    }
    __syncthreads();   // A: gate pre-activations visible to w0

    if (w == 0) {
      __bf16* hs = lbase + (size_t)(t & 7) * 32 * HID;
      #pragma unroll
      for (int mt = 0; mt < 2; ++mt) {
        #pragma unroll
        for (int rg = 0; rg < 4; ++rg) {
          int row = q * 4 + rg;
          float r  = sigmoidf_(accA[mt][rg] + accB[mt][rg] + b_r);
          float zv = sigmoidf_(LZ[mt][row][c] + b_z);
          float nn = tanhf_(LNA[mt][row][c] + b_nx + r * (LNB[mt][row][c] + b_nh));
          float h  = (1.f - zv) * nn + zv * hprev[mt][rg];
          hprev[mt][rg] = h;
          unsigned short us = __builtin_bit_cast(unsigned short, (__bf16)h);
          int po = __shfl_xor((int)us, 1, 64);
          if ((c & 1) == 0) {
            uint32_t pv = (uint32_t)us | ((uint32_t)po << 16);
            int lr = mt * 16 + row;
            *(uint32_t*)(hs + (size_t)lr * HID + jj0 + c) = pv;       // plain -> L2
            LH[t & 1][((mt * 4 + q) * 4 + rg) * 8 + (c >> 1)] = pv;   // for w3
          }
        }
      }
      asm volatile("s_waitcnt vmcnt(0)" ::: "memory");   // L2 acks (fast, local)
      *(volatile int*)(ifl + slot * 32) = t + 1;         // plain flag post
    }
    __syncthreads();   // B: LH handoff to w3

    if (w == 3 && layer == 0 && valid) {
      // publish local h(t) to the global h0 array (sc1 write-through)
      uint32_t d[4];
      #pragma unroll
      for (int i = 0; i < 4; ++i) d[i] = LH[t & 1][l * 4 + i];
      #pragma unroll
      for (int i = 0; i < 4; ++i) {
        int di = l * 4 + i;
        int mt = di >> 7, qq = (di >> 5) & 3, rg = (di >> 3) & 3, cp = di & 7;
        int gr = bq * 32 + mt * 16 + qq * 4 + rg;
        uint32_t* gp = (uint32_t*)(h0g + ((size_t)t * BATCH + gr) * HID + jj0 + cp * 2);
        __hip_atomic_store(gp, d[i], __ATOMIC_RELAXED, __HIP_MEMORY_SCOPE_AGENT);
      }
      if (t < T_STEPS - 1) {
        asm volatile("s_waitcnt vmcnt(9)" ::: "memory"); // steps <= t-2 acked
        if (t >= 1)
          __hip_atomic_store(cfl + slot * 32, t - 1,
                             __ATOMIC_RELAXED, __HIP_MEMORY_SCOPE_AGENT);
      } else {
        asm volatile("s_waitcnt vmcnt(0)" ::: "memory"); // final full drain
        __hip_atomic_store(cfl + slot * 32, T_STEPS,
                           __ATOMIC_RELAXED, __HIP_MEMORY_SCOPE_AGENT);
      }
    }

    if (w < 3 && t + 1 < T_STEPS) {
      if (layer == 1) pollc(t + 2);   // h0 slab t+1 published & drained?
      phaseX(t + 1);                  // hides flag flight / detection
    }
  }
}

// yhat[b][o] = h1_last[b][:] . Wout[o][:] + bout[o]
// h1 last slab lives in the layer-1 rings' local windows (slab 255&7 = 7);
// kernel-end writeback of dirty L2 + this kernel's start-acquire make it visible.
__global__ __launch_bounds__(64) void outproj(const __bf16* __restrict__ larena,
                                              const float* __restrict__ Wout,
                                              const float* __restrict__ bout,
                                              float* __restrict__ out) {
  int b = blockIdx.x, o = threadIdx.x;
  int ring = 4 + (b >> 5);
  const __bf16* hr = larena + ((size_t)ring * 8 + 7) * 32 * HID + (size_t)(b & 31) * HID;
  const float* wr = Wout + (size_t)o * HID;
  float acc = bout[o];
  for (int k = 0; k < HID; k += 8) {
    bf16x8 h8 = *(const bf16x8*)(hr + k);
    #pragma unroll
    for (int j = 0; j < 8; ++j) acc += (float)h8[j] * wr[k + j];
  }
  out[b * 64 + o] = acc;
}

extern "C" void kernel_launch(void* const* d_in, const int* in_sizes, int n_in,
                              void* d_out, int out_size, void* d_ws, size_t ws_size,
                              hipStream_t stream) {
  const float* x    = (const float*)d_in[0];
  const float* Wih0 = (const float*)d_in[1];
  const float* Whh0 = (const float*)d_in[2];
  const float* bih0 = (const float*)d_in[3];
  const float* bhh0 = (const float*)d_in[4];
  const float* Wih1 = (const float*)d_in[5];
  const float* Whh1 = (const float*)d_in[6];
  const float* bih1 = (const float*)d_in[7];
  const float* bhh1 = (const float*)d_in[8];
  const float* Wout = (const float*)d_in[9];
  const float* bout = (const float*)d_in[10];

  char* ws = (char*)d_ws;
  // ws layout:
  //   [0, 32 MiB)          h0g: published h0 [256][128][512] bf16
  //   [32 MiB, 34 MiB)     larena: 8 rings x 8-slab local windows [32][512] bf16
  //   [34 MiB, +64 KiB)    control: claim[8] @+0, iflags @+1 KiB (32 KiB),
  //                        cflags @+33 KiB (16 KiB)
  __bf16* h0g = (__bf16*)ws;
  __bf16* lar = (__bf16*)(ws + 33554432);
  int* claim  = (int*)(ws + 35651584);
  int* ifl    = (int*)(ws + 35651584 + 1024);
  int* cfl    = (int*)(ws + 35651584 + 1024 + 32768);

  // zero the control region (ws is poisoned before every launch)
  (void)hipMemsetAsync(ws + 35651584, 0, 65536, stream);

  gru_xcd<<<256, 256, 0, stream>>>(x,
                                   Wih0, Whh0, bih0, bhh0,
                                   Wih1, Whh1, bih1, bhh1,
                                   h0g, lar, claim, ifl, cfl);

  outproj<<<128, 64, 0, stream>>>(lar, Wout, bout, (float*)d_out);
}

// Round 10
// 1823.565 us; speedup vs baseline: 1.8151x; 1.8151x over previous
//
#include <hip/hip_runtime.h>
#include <hip/hip_bf16.h>
#include <stdint.h>

typedef __attribute__((ext_vector_type(8))) __bf16 bf16x8;
typedef __attribute__((ext_vector_type(4))) float  floatx4;

#define T_STEPS 256
#define BATCH   128
#define HID     512

__device__ __forceinline__ float sigmoidf_(float x) { return 1.f / (1.f + __expf(-x)); }
__device__ __forceinline__ float tanhf_(float y) {
  float e = __expf(-2.f * fabsf(y));
  return copysignf((1.f - e) / (1.f + e), y);
}

// poll 64 per-producer flag lines (lane l watches line l) until all >= target.
template <int SLP>
__device__ __forceinline__ void pollline_(const int* base, int target) {
  while (1) {
    int v = __hip_atomic_load(base, __ATOMIC_RELAXED, __HIP_MEMORY_SCOPE_AGENT);
    if (__all(v >= target)) break;
    __builtin_amdgcn_s_sleep(SLP);
  }
  asm volatile("" ::: "memory");
}

// Fused 2-layer persistent GRU scan, software-pipelined across layers,
// with PER-WAVE decoupled synchronization (zero in-loop barriers).
// Grid = 256 blocks: [layer(2)][bg(2)][g(64)]; block (L,bg,g) owns hidden cols
// [8g,8g+8) for batch rows [64bg,64bg+64); wave w handles rows [64bg+16w,+16).
// Dataflow is wave-diagonal: consumer wave w reads ONLY rows written by
// producer wave w  =>  flags are per-(block,wave) private 128B lines; each wave
// drains its own h stores (vmcnt(0)), posts its own flag, polls only wave-w
// lines. No __syncthreads in the loop at all.
// h exchange: fresh time-major slab per step (t-indexed, addresses never
// reused => plain cached consumer loads can never be stale).
// Cross-layer: layer-1 wave w gates phaseX(t) on layer-0 wave-w flags >= t+1.
__global__ __launch_bounds__(256) void gru_fused(
    const float* __restrict__ x,                              // [128][256][256] fp32
    const float* __restrict__ Wih0, const float* __restrict__ Whh0,
    const float* __restrict__ bih0, const float* __restrict__ bhh0,
    const float* __restrict__ Wih1, const float* __restrict__ Whh1,
    const float* __restrict__ bih1, const float* __restrict__ bhh1,
    __bf16* __restrict__ h0base,                              // [256][128][512]
    __bf16* __restrict__ h1base,                              // [256][128][512]
    int* __restrict__ fl)                                     // [2][2][4][64][32]
{
  const int tid   = threadIdx.x;
  const int layer = blockIdx.x >> 7;
  const int bg    = (blockIdx.x >> 6) & 1;
  const int g     = blockIdx.x & 63;
  const int w = tid >> 6, l = tid & 63, c = l & 15, q = l >> 4;
  const int Kin = layer ? HID : 256;
  const int KTx = Kin >> 5;            // 8 or 16
  const int KT  = KTx + 16;
  const int rowbase = bg * 64 + w * 16;
  const int jj  = g * 8 + c;

  const float* Wih = layer ? Wih1 : Wih0;
  const float* Whh = layer ? Whh1 : Whh0;
  const float* bih = layer ? bih1 : bih0;
  const float* bhh = layer ? bhh1 : bhh0;
  __bf16* hbase = layer ? h1base : h0base;

  __shared__ __bf16 ldsW[2 * 32 * 64 * 8];   // 64 KiB max (KT<=32)

  // ---- stage W slice (fp32 -> bf16) into frag-order LDS
  // tile0 cols: [r0..7 | z0..7], tile1 cols: [n0..7 | zeros]
  for (int cid = tid; cid < 2 * KT * 64; cid += 256) {
    int nt = cid / (KT * 64);
    int r1 = cid - nt * (KT * 64);
    int kt = r1 >> 6;
    int ll = r1 & 63;
    int cc = ll & 15, qq = ll >> 4;
    int k  = kt * 32 + qq * 8;
    int grow;
    if (nt == 0) grow = (cc < 8) ? (g * 8 + cc) : (512 + g * 8 + (cc - 8));
    else         grow = (cc < 8) ? (1024 + g * 8 + cc) : -1;
    bf16x8 v;
    if (grow >= 0) {
      const float* src = (k < Kin) ? (Wih + (size_t)grow * Kin + k)
                                   : (Whh + (size_t)grow * HID + (k - Kin));
      #pragma unroll
      for (int j = 0; j < 8; ++j) v[j] = (__bf16)src[j];
    } else {
      #pragma unroll
      for (int j = 0; j < 8; ++j) v[j] = (__bf16)0.f;
    }
    *(bf16x8*)&ldsW[((size_t)(nt * KT + kt) * 64 + ll) * 8] = v;
  }
  __syncthreads();   // the ONLY barrier; ldsW is read-only afterwards

  // ---- hoist the h-part W fragments
  bf16x8 WH[16][2];
  #pragma unroll
  for (int kt = 0; kt < 16; ++kt) {
    WH[kt][0] = *(const bf16x8*)&ldsW[((size_t)(0 * KT + KTx + kt) * 64 + l) * 8];
    WH[kt][1] = *(const bf16x8*)&ldsW[((size_t)(1 * KT + KTx + kt) * 64 + l) * 8];
  }

  // ---- per-lane biases
  float bias0, bias_nx, bias_nh;
  if (c < 8) {
    bias0   = bih[jj] + bhh[jj];
    bias_nx = bih[1024 + jj];
    bias_nh = bhh[1024 + jj];
  } else {
    int j2 = g * 8 + (c - 8);
    bias0   = bih[512 + j2] + bhh[512 + j2];
    bias_nx = 0.f; bias_nh = 0.f;
  }

  floatx4 accA[2], accB[2];
  const floatx4 zero4 = {0.f, 0.f, 0.f, 0.f};
  float hprev[4] = {0.f, 0.f, 0.f, 0.f};

  // per-(block,wave) flag lines: fl[layer][bg][w][g][32]
  int* fpost      = fl + ((((size_t)(layer * 2 + bg) * 4 + w) * 64) + g) * 32;
  const int* fown = fl + ((((size_t)(layer * 2 + bg) * 4 + w) * 64) + l) * 32;
  const int* fx   = fl + ((((size_t)(0 * 2 + bg) * 4 + w) * 64) + l) * 32;

  auto hslab = [&](int t) -> __bf16* {
    return hbase + (size_t)t * (BATCH * HID);
  };

  auto phaseX = [&](int t) {
    accA[0] = zero4; accA[1] = zero4;
    if (layer == 0) {
      const float* xp = x + ((size_t)(rowbase + c) * T_STEPS + t) * 256 + q * 8;
      for (int kt = 0; kt < 8; ++kt) {
        bf16x8 b0 = *(const bf16x8*)&ldsW[((size_t)(0 * KT + kt) * 64 + l) * 8];
        bf16x8 b1 = *(const bf16x8*)&ldsW[((size_t)(1 * KT + kt) * 64 + l) * 8];
        floatx4 u = *(const floatx4*)(xp + kt * 32);
        floatx4 v = *(const floatx4*)(xp + kt * 32 + 4);
        bf16x8 a;
        a[0] = (__bf16)u[0]; a[1] = (__bf16)u[1]; a[2] = (__bf16)u[2]; a[3] = (__bf16)u[3];
        a[4] = (__bf16)v[0]; a[5] = (__bf16)v[1]; a[6] = (__bf16)v[2]; a[7] = (__bf16)v[3];
        accA[0] = __builtin_amdgcn_mfma_f32_16x16x32_bf16(a, b0, accA[0], 0, 0, 0);
        accA[1] = __builtin_amdgcn_mfma_f32_16x16x32_bf16(a, b1, accA[1], 0, 0, 0);
      }
    } else {
      const __bf16* xp = h0base + (size_t)t * (BATCH * HID)
                       + (size_t)(rowbase + c) * HID + q * 8;
      for (int kt = 0; kt < 16; ++kt) {
        bf16x8 b0 = *(const bf16x8*)&ldsW[((size_t)(0 * KT + kt) * 64 + l) * 8];
        bf16x8 b1 = *(const bf16x8*)&ldsW[((size_t)(1 * KT + kt) * 64 + l) * 8];
        bf16x8 a = *(const bf16x8*)(xp + kt * 32);
        accA[0] = __builtin_amdgcn_mfma_f32_16x16x32_bf16(a, b0, accA[0], 0, 0, 0);
        accA[1] = __builtin_amdgcn_mfma_f32_16x16x32_bf16(a, b1, accA[1], 0, 0, 0);
      }
    }
  };

  // ---- prologue
  if (layer == 1) pollline_<2>(fx, 1);
  phaseX(0);

  for (int t = 0; t < T_STEPS; ++t) {
    // ---- phase H: accB = h_{t-1} @ Whh_slice^T (plain cached b128 loads)
    accB[0] = zero4; accB[1] = zero4;
    if (t > 0) {
      const __bf16* hA = hslab(t - 1) + (size_t)(rowbase + c) * HID + q * 8;
      bf16x8 hfrag[16];
      #pragma unroll
      for (int kt = 0; kt < 16; ++kt)
        hfrag[kt] = *(const bf16x8*)(hA + kt * 32);
      #pragma unroll
      for (int kt = 0; kt < 16; ++kt) {
        accB[0] = __builtin_amdgcn_mfma_f32_16x16x32_bf16(hfrag[kt], WH[kt][0], accB[0], 0, 0, 0);
        accB[1] = __builtin_amdgcn_mfma_f32_16x16x32_bf16(hfrag[kt], WH[kt][1], accB[1], 0, 0, 0);
      }
    }

    // ---- epilogue: gates + h update; packed-pair agent stores (write-through)
    __bf16* hs = hslab(t);
    #pragma unroll
    for (int rg = 0; rg < 4; ++rg) {
      float pre0 = accA[0][rg] + accB[0][rg] + bias0;
      float zs = __shfl(pre0, (l & 48) | ((c + 8) & 15), 64);
      float r  = sigmoidf_(pre0);
      float z  = sigmoidf_(zs);
      float nn = tanhf_(accA[1][rg] + bias_nx + r * (accB[1][rg] + bias_nh));
      float hnew = (1.f - z) * nn + z * hprev[rg];
      hprev[rg] = hnew;
      unsigned short us = __builtin_bit_cast(unsigned short, (__bf16)hnew);
      int po = __shfl_xor((int)us, 1, 64);
      if (c < 8 && (c & 1) == 0) {
        uint32_t v = (uint32_t)us | ((uint32_t)po << 16);
        int row = rowbase + q * 4 + rg;
        __hip_atomic_store((uint32_t*)(hs + (size_t)row * HID + jj), v,
                           __ATOMIC_RELAXED, __HIP_MEMORY_SCOPE_AGENT);
      }
    }

    // drain THIS WAVE's h stores, then publish this wave's step-t completion
    asm volatile("s_waitcnt vmcnt(0)" ::: "memory");
    if ((tid & 63) == 0)
      __hip_atomic_store(fpost, t + 1, __ATOMIC_RELAXED, __HIP_MEMORY_SCOPE_AGENT);

    if (t + 1 < T_STEPS) {
      if (layer == 1) pollline_<2>(fx, t + 2);  // h0 slab t+1 ready (wave-w rows)?
      phaseX(t + 1);                            // hides flag flight / detection
      pollline_<1>(fown, t + 1);                // wave-w peers' h_t visible?
    }
  }
}

// yhat[b][o] = h1_last[b][:] . Wout[o][:] + bout[o]
__global__ __launch_bounds__(64) void outproj(const __bf16* __restrict__ h1,
                                              const float* __restrict__ Wout,
                                              const float* __restrict__ bout,
                                              float* __restrict__ out) {
  int b = blockIdx.x, o = threadIdx.x;
  const __bf16* hr = h1 + (size_t)b * HID;
  const float*  wr = Wout + (size_t)o * HID;
  float acc = bout[o];
  for (int k = 0; k < HID; k += 8) {
    bf16x8 h8 = *(const bf16x8*)(hr + k);
    #pragma unroll
    for (int j = 0; j < 8; ++j) acc += (float)h8[j] * wr[k + j];
  }
  out[b * 64 + o] = acc;
}

extern "C" void kernel_launch(void* const* d_in, const int* in_sizes, int n_in,
                              void* d_out, int out_size, void* d_ws, size_t ws_size,
                              hipStream_t stream) {
  const float* x    = (const float*)d_in[0];
  const float* Wih0 = (const float*)d_in[1];
  const float* Whh0 = (const float*)d_in[2];
  const float* bih0 = (const float*)d_in[3];
  const float* bhh0 = (const float*)d_in[4];
  const float* Wih1 = (const float*)d_in[5];
  const float* Whh1 = (const float*)d_in[6];
  const float* bih1 = (const float*)d_in[7];
  const float* bhh1 = (const float*)d_in[8];
  const float* Wout = (const float*)d_in[9];
  const float* bout = (const float*)d_in[10];

  char* ws = (char*)d_ws;
  // ws layout (bytes):
  //   [0, 32 MiB)        h0seq: 256 slabs x 128 KB ([t][b][512] bf16)
  //   [32 MiB, 64 MiB)   h1seq: 256 slabs x 128 KB
  //   [64 MiB, +256 KiB) flags [2 layer][2 bg][4 wave][64 g][32 ints]
  __bf16* h0 = (__bf16*)(ws);
  __bf16* h1 = (__bf16*)(ws + (32u << 20));
  int*    fl = (int*)(ws + (64u << 20));

  // zero the flag lines (ws is poisoned before every launch)
  (void)hipMemsetAsync(fl, 0, 2 * 2 * 4 * 64 * 32 * 4, stream);

  // fused 2-layer pipelined scan: blocks [0,128) = layer 0, [128,256) = layer 1
  gru_fused<<<256, 256, 0, stream>>>(x,
                                     Wih0, Whh0, bih0, bhh0,
                                     Wih1, Whh1, bih1, bhh1,
                                     h0, h1, fl);

  // final h1 = slab 255
  outproj<<<128, 64, 0, stream>>>(h1 + (size_t)255 * BATCH * HID,
                                  Wout, bout, (float*)d_out);
}